// Round 1
// baseline (1527.248 us; speedup 1.0000x reference)
//
#include <hip/hip_runtime.h>
#include <math.h>

#define F_IN 128
#define HID  128
#define CDIM 64
#define BN_EPS 1e-5f

// ---------------------------------------------------------------------------
// GEMM1: Y[N,128] = X[N,128] @ W[128,128]. W staged in LDS (64 KB).
// Block = 256 threads = 2 rows x 128 cols per iteration, grid-stride over rows.
// LDS read Wl[k*128+col]: wave lanes cover 64 consecutive cols -> 2 lanes/bank
// (free on gfx950, m136). xs[rl][k] is a broadcast.
// ---------------------------------------------------------------------------
__global__ __launch_bounds__(256) void gemm_xw1(const float* __restrict__ X,
                                                const float* __restrict__ W,
                                                float* __restrict__ Y, int N) {
    __shared__ float Wl[HID * F_IN];   // 64 KB
    __shared__ float xs[2][F_IN];
    for (int i = threadIdx.x; i < F_IN * HID; i += 256) Wl[i] = W[i];
    const int col = threadIdx.x & 127;
    const int rl  = threadIdx.x >> 7;   // 0 or 1
    for (int row0 = blockIdx.x * 2; row0 < N; row0 += gridDim.x * 2) {
        __syncthreads();               // covers W-load on iter 0, xs reuse after
        int r = row0 + rl;
        xs[rl][col] = (r < N) ? X[(size_t)r * F_IN + col] : 0.f;
        __syncthreads();
        float acc = 0.f;
        #pragma unroll 8
        for (int k = 0; k < F_IN; ++k)
            acc = fmaf(xs[rl][k], Wl[k * HID + col], acc);
        if (r < N) Y[(size_t)r * HID + col] = acc;
    }
}

// ---------------------------------------------------------------------------
// GEMM2: Y[N,64] = X[N,128] @ W[128,64]. Block = 4 rows x 64 cols.
// ---------------------------------------------------------------------------
__global__ __launch_bounds__(256) void gemm_xw2(const float* __restrict__ X,
                                                const float* __restrict__ W,
                                                float* __restrict__ Y, int N) {
    __shared__ float Wl[HID * CDIM];   // 32 KB
    __shared__ float xs[4][HID];       // 2 KB
    for (int i = threadIdx.x; i < HID * CDIM; i += 256) Wl[i] = W[i];
    const int col = threadIdx.x & 63;
    const int rl  = threadIdx.x >> 6;  // 0..3
    for (int row0 = blockIdx.x * 4; row0 < N; row0 += gridDim.x * 4) {
        __syncthreads();
        // load 4 rows x 128 = 512 floats with 256 threads (2 each)
        int i0 = threadIdx.x, i1 = threadIdx.x + 256;
        int r0 = row0 + (i0 >> 7);
        xs[i0 >> 7][i0 & 127] = (r0 < N) ? X[(size_t)r0 * HID + (i0 & 127)] : 0.f;
        int r1 = row0 + (i1 >> 7);
        xs[i1 >> 7][i1 & 127] = (r1 < N) ? X[(size_t)r1 * HID + (i1 & 127)] : 0.f;
        __syncthreads();
        float acc = 0.f;
        #pragma unroll 8
        for (int k = 0; k < HID; ++k)
            acc = fmaf(xs[rl][k], Wl[k * CDIM + col], acc);
        int row = row0 + rl;
        if (row < N) Y[(size_t)row * CDIM + col] = acc;
    }
}

// ---------------------------------------------------------------------------
// Edge scatter: AGG[dst, :] += XW[src, :] * w[e], one thread per (edge, feat).
// Consecutive threads share an edge -> coalesced row access, broadcast e-loads.
// ---------------------------------------------------------------------------
template <int LOGD>
__global__ __launch_bounds__(256) void scatter_kernel(
        const float* __restrict__ XW, const int* __restrict__ src,
        const int* __restrict__ dst, const float* __restrict__ w,
        float* __restrict__ AGG, long long total) {
    const int D = 1 << LOGD;
    long long gid = (long long)blockIdx.x * blockDim.x + threadIdx.x;
    long long stride = (long long)gridDim.x * blockDim.x;
    for (; gid < total; gid += stride) {
        int e = (int)(gid >> LOGD);
        int f = (int)(gid & (D - 1));
        int s = src[e], d = dst[e];
        float val = XW[(size_t)s * D + f] * w[e];
        atomicAdd(&AGG[(size_t)d * D + f], val);
    }
}

// ---------------------------------------------------------------------------
// BN (eval) + ReLU, fused with +b1:  h = relu(scale*(agg+b1-mean)+beta)
// ---------------------------------------------------------------------------
__global__ __launch_bounds__(256) void bn_relu_kernel(
        const float* __restrict__ AGG, const float* __restrict__ b1,
        const float* __restrict__ gamma, const float* __restrict__ beta,
        const float* __restrict__ mean, const float* __restrict__ var,
        float* __restrict__ H, long long total) {
    __shared__ float scale_s[HID], shift_s[HID];
    if (threadIdx.x < HID) {
        float sc = gamma[threadIdx.x] * rsqrtf(var[threadIdx.x] + BN_EPS);
        scale_s[threadIdx.x] = sc;
        shift_s[threadIdx.x] = beta[threadIdx.x] + sc * (b1[threadIdx.x] - mean[threadIdx.x]);
    }
    __syncthreads();
    long long gid = (long long)blockIdx.x * blockDim.x + threadIdx.x;
    long long stride = (long long)gridDim.x * blockDim.x;
    for (; gid < total; gid += stride) {
        int f = (int)(gid & (HID - 1));
        float v = fmaf(AGG[gid], scale_s[f], shift_s[f]);
        H[gid] = v > 0.f ? v : 0.f;
    }
}

// ---------------------------------------------------------------------------
// Epilogue: h = agg2 + b2; delta-merge with masks; log_softmax over 64 cols.
// One wave (64 lanes) per row; AGG2 aliases out_emb (in-place, per-element).
// ---------------------------------------------------------------------------
__global__ __launch_bounds__(256) void final_kernel(
        const float* __restrict__ AGG2, const float* __restrict__ b2,
        const float* __restrict__ prev, const int* __restrict__ sens,
        const int* __restrict__ ins, float* __restrict__ out_lsm,
        float* __restrict__ out_emb, int N) {
    int r = blockIdx.x * 4 + (threadIdx.x >> 6);
    if (r >= N) return;                       // wave-uniform exit
    int f = threadIdx.x & 63;
    float h = AGG2[(size_t)r * CDIM + f] + b2[f];
    bool s_ = sens[r] != 0;
    bool i_ = ins[r] != 0;
    float o = (s_ ? h : prev[(size_t)r * CDIM + f]) + (i_ ? h : 0.f);
    // 64-lane log-softmax
    float m = o;
    #pragma unroll
    for (int off = 32; off > 0; off >>= 1) m = fmaxf(m, __shfl_xor(m, off, 64));
    float e = expf(o - m);
    float sum = e;
    #pragma unroll
    for (int off = 32; off > 0; off >>= 1) sum += __shfl_xor(sum, off, 64);
    float lsm = o - m - logf(sum);
    out_lsm[(size_t)r * CDIM + f] = lsm;
    out_emb[(size_t)r * CDIM + f] = o;
}

extern "C" void kernel_launch(void* const* d_in, const int* in_sizes, int n_in,
                              void* d_out, int out_size, void* d_ws, size_t ws_size,
                              hipStream_t stream) {
    const float* features = (const float*)d_in[0];
    const int*   esrc     = (const int*)d_in[1];
    const int*   edst     = (const int*)d_in[2];
    const float* ew       = (const float*)d_in[3];
    const float* W1       = (const float*)d_in[4];
    const float* b1       = (const float*)d_in[5];
    const float* gamma1   = (const float*)d_in[6];
    const float* beta1    = (const float*)d_in[7];
    const float* mean1    = (const float*)d_in[8];
    const float* var1     = (const float*)d_in[9];
    const float* W2       = (const float*)d_in[10];
    const float* b2       = (const float*)d_in[11];
    const float* prev     = (const float*)d_in[12];
    const int*   sens     = (const int*)d_in[13];
    const int*   ins      = (const int*)d_in[14];

    const int N = in_sizes[0] / F_IN;
    const int E = in_sizes[1];

    // Workspace layout (fp32): xw1 [N*128] | agg1 [N*128] (reused as xw2)
    float* xw1  = (float*)d_ws;
    float* agg1 = xw1 + (size_t)N * HID;
    // d_out layout: out_lsm [N*64] | out_emb [N*64]; agg2 aliases out_emb.
    float* out_lsm = (float*)d_out;
    float* out_emb = out_lsm + (size_t)N * CDIM;
    float* agg2    = out_emb;

    hipMemsetAsync(agg1, 0, (size_t)N * HID * sizeof(float), stream);
    hipMemsetAsync(agg2, 0, (size_t)N * CDIM * sizeof(float), stream);

    gemm_xw1<<<4096, 256, 0, stream>>>(features, W1, xw1, N);

    long long tot1 = (long long)E * HID;
    scatter_kernel<7><<<(int)((tot1 + 255) / 256), 256, 0, stream>>>(
        xw1, esrc, edst, ew, agg1, tot1);

    long long totbn = (long long)N * HID;
    bn_relu_kernel<<<(int)((totbn + 255) / 256), 256, 0, stream>>>(
        agg1, b1, gamma1, beta1, mean1, var1, xw1, totbn);  // H written over xw1

    gemm_xw2<<<4096, 256, 0, stream>>>(xw1, W2, agg1, N);   // xw2 over agg1

    long long tot2 = (long long)E * CDIM;
    scatter_kernel<6><<<(int)((tot2 + 255) / 256), 256, 0, stream>>>(
        agg1, esrc, edst, ew, agg2, tot2);

    final_kernel<<<(N + 3) / 4, 256, 0, stream>>>(
        agg2, b2, prev, sens, ins, out_lsm, out_emb, N);
}

// Round 2
// 853.227 us; speedup vs baseline: 1.7900x; 1.7900x over previous
//
#include <hip/hip_runtime.h>
#include <math.h>

#define F_IN 128
#define HID  128
#define CDIM 64
#define BN_EPS 1e-5f
#define SCAN_CHUNK 1024   // elements per scan block (256 thr x 4)

// ---------------------------------------------------------------------------
// GEMM1: Y[N,128] = X[N,128] @ W[128,128]. W staged in LDS.
// ---------------------------------------------------------------------------
__global__ __launch_bounds__(256) void gemm_xw1(const float* __restrict__ X,
                                                const float* __restrict__ W,
                                                float* __restrict__ Y, int N) {
    __shared__ float Wl[HID * F_IN];   // 64 KB
    __shared__ float xs[2][F_IN];
    for (int i = threadIdx.x; i < F_IN * HID; i += 256) Wl[i] = W[i];
    const int col = threadIdx.x & 127;
    const int rl  = threadIdx.x >> 7;
    for (int row0 = blockIdx.x * 2; row0 < N; row0 += gridDim.x * 2) {
        __syncthreads();
        int r = row0 + rl;
        xs[rl][col] = (r < N) ? X[(size_t)r * F_IN + col] : 0.f;
        __syncthreads();
        float acc = 0.f;
        #pragma unroll 8
        for (int k = 0; k < F_IN; ++k)
            acc = fmaf(xs[rl][k], Wl[k * HID + col], acc);
        if (r < N) Y[(size_t)r * HID + col] = acc;
    }
}

// ---------------------------------------------------------------------------
// GEMM2: Y[N,64] = H[N,128] @ W[128,64].
// ---------------------------------------------------------------------------
__global__ __launch_bounds__(256) void gemm_xw2(const float* __restrict__ X,
                                                const float* __restrict__ W,
                                                float* __restrict__ Y, int N) {
    __shared__ float Wl[HID * CDIM];   // 32 KB
    __shared__ float xs[4][HID];
    for (int i = threadIdx.x; i < HID * CDIM; i += 256) Wl[i] = W[i];
    const int col = threadIdx.x & 63;
    const int rl  = threadIdx.x >> 6;
    for (int row0 = blockIdx.x * 4; row0 < N; row0 += gridDim.x * 4) {
        __syncthreads();
        int i0 = threadIdx.x, i1 = threadIdx.x + 256;
        int r0 = row0 + (i0 >> 7);
        xs[i0 >> 7][i0 & 127] = (r0 < N) ? X[(size_t)r0 * HID + (i0 & 127)] : 0.f;
        int r1 = row0 + (i1 >> 7);
        xs[i1 >> 7][i1 & 127] = (r1 < N) ? X[(size_t)r1 * HID + (i1 & 127)] : 0.f;
        __syncthreads();
        float acc = 0.f;
        #pragma unroll 8
        for (int k = 0; k < HID; ++k)
            acc = fmaf(xs[rl][k], Wl[k * CDIM + col], acc);
        int row = row0 + rl;
        if (row < N) Y[(size_t)row * CDIM + col] = acc;
    }
}

// ---------------------------------------------------------------------------
// CSR build step 1: histogram of dst.  counts must be pre-zeroed.
// ---------------------------------------------------------------------------
__global__ __launch_bounds__(256) void hist_kernel(const int* __restrict__ dst,
                                                   int* __restrict__ counts, int E) {
    int gid = blockIdx.x * 256 + threadIdx.x;
    int stride = gridDim.x * 256;
    for (; gid < E; gid += stride) atomicAdd(&counts[dst[gid]], 1);
}

// CSR build step 2a: per-chunk (1024-elem) sums.
__global__ __launch_bounds__(256) void scan_sums(const int* __restrict__ counts,
                                                 int* __restrict__ bsums, int N) {
    __shared__ int sdata[256];
    int base = blockIdx.x * SCAN_CHUNK + threadIdx.x * 4;
    int t = 0;
    #pragma unroll
    for (int j = 0; j < 4; ++j) { int i = base + j; if (i < N) t += counts[i]; }
    sdata[threadIdx.x] = t; __syncthreads();
    for (int off = 128; off > 0; off >>= 1) {
        if (threadIdx.x < off) sdata[threadIdx.x] += sdata[threadIdx.x + off];
        __syncthreads();
    }
    if (threadIdx.x == 0) bsums[blockIdx.x] = sdata[0];
}

// CSR build step 2b: serial exclusive scan of block sums (nb ~ 98, trivial).
__global__ void scan_offsets(const int* __restrict__ bsums, int* __restrict__ boffs,
                             int nb, int* __restrict__ row_ptr, int N, int E) {
    if (threadIdx.x == 0 && blockIdx.x == 0) {
        int run = 0;
        for (int i = 0; i < nb; ++i) { boffs[i] = run; run += bsums[i]; }
        row_ptr[N] = E;
    }
}

// CSR build step 2c: per-chunk exclusive scan + block offset -> row_ptr, cursor.
// NOTE: counts aliases cursor — all loads complete before first barrier, writes after.
__global__ __launch_bounds__(256) void scan_write(const int* __restrict__ counts,
                                                  const int* __restrict__ boffs,
                                                  int* __restrict__ row_ptr,
                                                  int* __restrict__ cursor, int N) {
    __shared__ int sdata[256];
    int base = blockIdx.x * SCAN_CHUNK + threadIdx.x * 4;
    int v[4]; int tsum = 0;
    #pragma unroll
    for (int j = 0; j < 4; ++j) {
        int i = base + j;
        v[j] = (i < N) ? counts[i] : 0;
        tsum += v[j];
    }
    sdata[threadIdx.x] = tsum; __syncthreads();
    // Hillis-Steele inclusive scan over 256 thread sums
    for (int off = 1; off < 256; off <<= 1) {
        int t = (threadIdx.x >= off) ? sdata[threadIdx.x - off] : 0;
        __syncthreads();
        sdata[threadIdx.x] += t;
        __syncthreads();
    }
    int off0 = sdata[threadIdx.x] - tsum + boffs[blockIdx.x];
    #pragma unroll
    for (int j = 0; j < 4; ++j) {
        int i = base + j;
        if (i < N) { row_ptr[i] = off0; cursor[i] = off0; off0 += v[j]; }
    }
}

// CSR build step 3: scatter edges into sorted position.
__global__ __launch_bounds__(256) void fill_kernel(const int* __restrict__ src,
                                                   const int* __restrict__ dst,
                                                   const float* __restrict__ w,
                                                   int* __restrict__ cursor,
                                                   int* __restrict__ src_s,
                                                   float* __restrict__ w_s, int E) {
    int gid = blockIdx.x * 256 + threadIdx.x;
    int stride = gridDim.x * 256;
    for (; gid < E; gid += stride) {
        int d = dst[gid];
        int pos = atomicAdd(&cursor[d], 1);
        src_s[pos] = src[gid];
        w_s[pos]   = w[gid];
    }
}

// Precompute BN scale/shift (fused with +b1): h = relu(scale*agg + shift)
__global__ void bn_prep(const float* __restrict__ b1, const float* __restrict__ gamma,
                        const float* __restrict__ beta, const float* __restrict__ mean,
                        const float* __restrict__ var, float* __restrict__ scale,
                        float* __restrict__ shift) {
    int f = threadIdx.x;
    if (f < HID) {
        float sc = gamma[f] * rsqrtf(var[f] + BN_EPS);
        scale[f] = sc;
        shift[f] = beta[f] + sc * (b1[f] - mean[f]);
    }
}

// ---------------------------------------------------------------------------
// Gather layer 1 (D=128): one 128-thread block per dst row. No atomics.
// Fused BN+ReLU epilogue. Register accumulation, one coalesced row write.
// ---------------------------------------------------------------------------
__global__ __launch_bounds__(128) void gather1_kernel(
        const float* __restrict__ XW, const int* __restrict__ row_ptr,
        const int* __restrict__ src_s, const float* __restrict__ w_s,
        const float* __restrict__ scale, const float* __restrict__ shift,
        float* __restrict__ H, int N) {
    __shared__ int   s_src[128];
    __shared__ float s_w[128];
    int d = blockIdx.x;
    int f = threadIdx.x;
    int beg = row_ptr[d], end = row_ptr[d + 1];
    float acc = 0.f;
    for (int base = beg; base < end; base += 128) {
        int m = end - base; if (m > 128) m = 128;
        if (f < m) { s_src[f] = src_s[base + f]; s_w[f] = w_s[base + f]; }
        __syncthreads();
        for (int k = 0; k < m; ++k)
            acc = fmaf(XW[(size_t)s_src[k] * HID + f], s_w[k], acc);
        __syncthreads();
    }
    float hv = fmaf(acc, scale[f], shift[f]);
    H[(size_t)d * HID + f] = hv > 0.f ? hv : 0.f;
}

// ---------------------------------------------------------------------------
// Gather layer 2 (D=64) + full epilogue: one wave per dst row, 4 rows/block.
// Edge data broadcast via shuffles; log_softmax via 64-lane butterflies.
// ---------------------------------------------------------------------------
__global__ __launch_bounds__(256) void gather2_final(
        const float* __restrict__ XW2, const int* __restrict__ row_ptr,
        const int* __restrict__ src_s, const float* __restrict__ w_s,
        const float* __restrict__ b2, const float* __restrict__ prev,
        const int* __restrict__ sens, const int* __restrict__ ins,
        float* __restrict__ out_lsm, float* __restrict__ out_emb, int N) {
    int r = blockIdx.x * 4 + (threadIdx.x >> 6);
    if (r >= N) return;                     // wave-uniform
    int f = threadIdx.x & 63;
    int beg = row_ptr[r], end = row_ptr[r + 1];
    float acc = 0.f;
    for (int base = beg; base < end; base += 64) {
        int m = end - base; if (m > 64) m = 64;
        int   se = (f < m) ? src_s[base + f] : 0;
        float we = (f < m) ? w_s[base + f] : 0.f;
        for (int k = 0; k < m; ++k) {
            int   sk = __shfl(se, k, 64);
            float wk = __shfl(we, k, 64);
            acc = fmaf(XW2[(size_t)sk * CDIM + f], wk, acc);
        }
    }
    float h = acc + b2[f];
    bool s_ = sens[r] != 0;
    bool i_ = ins[r] != 0;
    float o = (s_ ? h : prev[(size_t)r * CDIM + f]) + (i_ ? h : 0.f);
    float m = o;
    #pragma unroll
    for (int off = 32; off > 0; off >>= 1) m = fmaxf(m, __shfl_xor(m, off, 64));
    float e = expf(o - m);
    float sum = e;
    #pragma unroll
    for (int off = 32; off > 0; off >>= 1) sum += __shfl_xor(sum, off, 64);
    out_lsm[(size_t)r * CDIM + f] = o - m - logf(sum);
    out_emb[(size_t)r * CDIM + f] = o;
}

extern "C" void kernel_launch(void* const* d_in, const int* in_sizes, int n_in,
                              void* d_out, int out_size, void* d_ws, size_t ws_size,
                              hipStream_t stream) {
    const float* features = (const float*)d_in[0];
    const int*   esrc     = (const int*)d_in[1];
    const int*   edst     = (const int*)d_in[2];
    const float* ew       = (const float*)d_in[3];
    const float* W1       = (const float*)d_in[4];
    const float* b1       = (const float*)d_in[5];
    const float* gamma1   = (const float*)d_in[6];
    const float* beta1    = (const float*)d_in[7];
    const float* mean1    = (const float*)d_in[8];
    const float* var1     = (const float*)d_in[9];
    const float* W2       = (const float*)d_in[10];
    const float* b2       = (const float*)d_in[11];
    const float* prev     = (const float*)d_in[12];
    const int*   sens     = (const int*)d_in[13];
    const int*   ins      = (const int*)d_in[14];

    const int N = in_sizes[0] / F_IN;
    const int E = in_sizes[1];
    const int nb = (N + SCAN_CHUNK - 1) / SCAN_CHUNK;

    // ---- workspace layout (fp32 words) ----
    float* xw1   = (float*)d_ws;                 // N*128  (later reused as xw2: N*64)
    float* h     = xw1 + (size_t)N * HID;        // N*128
    float* scale = h + (size_t)N * HID;          // 128
    float* shift = scale + HID;                  // 128
    int* row_ptr = (int*)(shift + HID);          // N+1
    int* cursor  = row_ptr + (N + 1);            // N   (aliases counts)
    int* bsums   = cursor + N;                   // nb
    int* boffs   = bsums + nb;                   // nb
    int* src_s   = boffs + nb;                   // E
    float* w_s   = (float*)(src_s + E);          // E
    float* xw2   = xw1;                          // alias: xw1 dead after gather1

    float* out_lsm = (float*)d_out;
    float* out_emb = out_lsm + (size_t)N * CDIM;

    // ---- CSR build (shared by both layers) ----
    hipMemsetAsync(cursor, 0, (size_t)N * sizeof(int), stream);   // counts = 0
    hist_kernel<<<(E + 255) / 256, 256, 0, stream>>>(edst, cursor, E);
    scan_sums<<<nb, 256, 0, stream>>>(cursor, bsums, N);
    scan_offsets<<<1, 64, 0, stream>>>(bsums, boffs, nb, row_ptr, N, E);
    scan_write<<<nb, 256, 0, stream>>>(cursor, boffs, row_ptr, cursor, N);
    fill_kernel<<<(E + 255) / 256, 256, 0, stream>>>(esrc, edst, ew, cursor,
                                                     src_s, w_s, E);
    bn_prep<<<1, 128, 0, stream>>>(b1, gamma1, beta1, mean1, var1, scale, shift);

    // ---- layer 1 ----
    gemm_xw1<<<4096, 256, 0, stream>>>(features, W1, xw1, N);
    gather1_kernel<<<N, 128, 0, stream>>>(xw1, row_ptr, src_s, w_s,
                                          scale, shift, h, N);
    // ---- layer 2 ----
    gemm_xw2<<<4096, 256, 0, stream>>>(h, W2, xw2, N);
    gather2_final<<<(N + 3) / 4, 256, 0, stream>>>(xw2, row_ptr, src_s, w_s,
                                                   b2, prev, sens, ins,
                                                   out_lsm, out_emb, N);
}

// Round 3
// 679.904 us; speedup vs baseline: 2.2463x; 1.2549x over previous
//
#include <hip/hip_runtime.h>
#include <math.h>

#define F_IN 128
#define HID  128
#define CDIM 64
#define BN_EPS 1e-5f
#define SCAN_CHUNK 1024   // elements per scan block (256 thr x 4)

// ---------------------------------------------------------------------------
// GEMM1: Y[N,128] = X[N,128] @ W[128,128].
// Tile: 128 rows x 128 cols per block, K chunked by 64. Micro-tile 8x8.
// LDS 64 KB -> 2 blocks/CU. B-read 0.5 B/FMA -> VALU-bound.
// ---------------------------------------------------------------------------
__global__ __launch_bounds__(256) void gemm_xw1(const float* __restrict__ X,
                                                const float* __restrict__ W,
                                                float* __restrict__ Y, int N) {
    __shared__ float Wl[64][128];    // 32 KB : K-chunk of W
    __shared__ float xs[128][64];    // 32 KB : row tile x K-chunk
    const int cg = (threadIdx.x & 15) * 8;   // col group
    const int rg = (threadIdx.x >> 4) * 8;   // row group
    const int ntiles = (N + 127) >> 7;
    for (int tile = blockIdx.x; tile < ntiles; tile += gridDim.x) {
        const int row0 = tile << 7;
        float acc[8][8];
        #pragma unroll
        for (int i = 0; i < 8; ++i)
            #pragma unroll
            for (int j = 0; j < 8; ++j) acc[i][j] = 0.f;

        for (int kc = 0; kc < 128; kc += 64) {
            __syncthreads();
            // stage W chunk: 64x128 floats as float4 (2048 float4, 8/thread)
            for (int i = threadIdx.x; i < 2048; i += 256) {
                int kr = i >> 5, c = (i & 31) * 4;
                *(float4*)&Wl[kr][c] = *(const float4*)&W[(size_t)(kc + kr) * HID + c];
            }
            // stage X chunk: 128 rows x 64 cols as float4 (2048 float4)
            for (int i = threadIdx.x; i < 2048; i += 256) {
                int r = i >> 4, c = (i & 15) * 4;
                int gr = row0 + r;
                float4 v = make_float4(0.f, 0.f, 0.f, 0.f);
                if (gr < N) v = *(const float4*)&X[(size_t)gr * F_IN + kc + c];
                *(float4*)&xs[r][c] = v;
            }
            __syncthreads();
            #pragma unroll 2
            for (int k = 0; k < 64; k += 2) {
                float2 a[8];
                #pragma unroll
                for (int i = 0; i < 8; ++i) a[i] = *(float2*)&xs[rg + i][k];
                float4 b00 = *(float4*)&Wl[k][cg];
                float4 b01 = *(float4*)&Wl[k][cg + 4];
                float4 b10 = *(float4*)&Wl[k + 1][cg];
                float4 b11 = *(float4*)&Wl[k + 1][cg + 4];
                #pragma unroll
                for (int i = 0; i < 8; ++i) {
                    acc[i][0] = fmaf(a[i].x, b00.x, acc[i][0]);
                    acc[i][1] = fmaf(a[i].x, b00.y, acc[i][1]);
                    acc[i][2] = fmaf(a[i].x, b00.z, acc[i][2]);
                    acc[i][3] = fmaf(a[i].x, b00.w, acc[i][3]);
                    acc[i][4] = fmaf(a[i].x, b01.x, acc[i][4]);
                    acc[i][5] = fmaf(a[i].x, b01.y, acc[i][5]);
                    acc[i][6] = fmaf(a[i].x, b01.z, acc[i][6]);
                    acc[i][7] = fmaf(a[i].x, b01.w, acc[i][7]);
                    acc[i][0] = fmaf(a[i].y, b10.x, acc[i][0]);
                    acc[i][1] = fmaf(a[i].y, b10.y, acc[i][1]);
                    acc[i][2] = fmaf(a[i].y, b10.z, acc[i][2]);
                    acc[i][3] = fmaf(a[i].y, b10.w, acc[i][3]);
                    acc[i][4] = fmaf(a[i].y, b11.x, acc[i][4]);
                    acc[i][5] = fmaf(a[i].y, b11.y, acc[i][5]);
                    acc[i][6] = fmaf(a[i].y, b11.z, acc[i][6]);
                    acc[i][7] = fmaf(a[i].y, b11.w, acc[i][7]);
                }
            }
        }
        #pragma unroll
        for (int i = 0; i < 8; ++i) {
            int gr = row0 + rg + i;
            if (gr < N) {
                *(float4*)&Y[(size_t)gr * HID + cg] =
                    make_float4(acc[i][0], acc[i][1], acc[i][2], acc[i][3]);
                *(float4*)&Y[(size_t)gr * HID + cg + 4] =
                    make_float4(acc[i][4], acc[i][5], acc[i][6], acc[i][7]);
            }
        }
    }
}

// ---------------------------------------------------------------------------
// GEMM2: Y[N,64] = H[N,128] @ W[128,64].
// Tile: 128 rows x 64 cols, K chunked by 64. Micro-tile 8x4. LDS 48 KB.
// ---------------------------------------------------------------------------
__global__ __launch_bounds__(256) void gemm_xw2(const float* __restrict__ X,
                                                const float* __restrict__ W,
                                                float* __restrict__ Y, int N) {
    __shared__ float Wl[64][64];     // 16 KB
    __shared__ float xs[128][64];    // 32 KB
    const int cg = (threadIdx.x & 15) * 4;
    const int rg = (threadIdx.x >> 4) * 8;
    const int ntiles = (N + 127) >> 7;
    for (int tile = blockIdx.x; tile < ntiles; tile += gridDim.x) {
        const int row0 = tile << 7;
        float acc[8][4];
        #pragma unroll
        for (int i = 0; i < 8; ++i)
            #pragma unroll
            for (int j = 0; j < 4; ++j) acc[i][j] = 0.f;

        for (int kc = 0; kc < 128; kc += 64) {
            __syncthreads();
            for (int i = threadIdx.x; i < 1024; i += 256) {          // W chunk
                int kr = i >> 4, c = (i & 15) * 4;
                *(float4*)&Wl[kr][c] = *(const float4*)&W[(size_t)(kc + kr) * CDIM + c];
            }
            for (int i = threadIdx.x; i < 2048; i += 256) {          // X chunk
                int r = i >> 4, c = (i & 15) * 4;
                int gr = row0 + r;
                float4 v = make_float4(0.f, 0.f, 0.f, 0.f);
                if (gr < N) v = *(const float4*)&X[(size_t)gr * HID + kc + c];
                *(float4*)&xs[r][c] = v;
            }
            __syncthreads();
            #pragma unroll 2
            for (int k = 0; k < 64; k += 2) {
                float2 a[8];
                #pragma unroll
                for (int i = 0; i < 8; ++i) a[i] = *(float2*)&xs[rg + i][k];
                float4 b0 = *(float4*)&Wl[k][cg];
                float4 b1 = *(float4*)&Wl[k + 1][cg];
                #pragma unroll
                for (int i = 0; i < 8; ++i) {
                    acc[i][0] = fmaf(a[i].x, b0.x, acc[i][0]);
                    acc[i][1] = fmaf(a[i].x, b0.y, acc[i][1]);
                    acc[i][2] = fmaf(a[i].x, b0.z, acc[i][2]);
                    acc[i][3] = fmaf(a[i].x, b0.w, acc[i][3]);
                    acc[i][0] = fmaf(a[i].y, b1.x, acc[i][0]);
                    acc[i][1] = fmaf(a[i].y, b1.y, acc[i][1]);
                    acc[i][2] = fmaf(a[i].y, b1.z, acc[i][2]);
                    acc[i][3] = fmaf(a[i].y, b1.w, acc[i][3]);
                }
            }
        }
        #pragma unroll
        for (int i = 0; i < 8; ++i) {
            int gr = row0 + rg + i;
            if (gr < N)
                *(float4*)&Y[(size_t)gr * CDIM + cg] =
                    make_float4(acc[i][0], acc[i][1], acc[i][2], acc[i][3]);
        }
    }
}

// ---------------------------------------------------------------------------
// CSR build: histogram -> scan -> fill (shared by both layers)
// ---------------------------------------------------------------------------
__global__ __launch_bounds__(256) void hist_kernel(const int* __restrict__ dst,
                                                   int* __restrict__ counts, int E) {
    int gid = blockIdx.x * 256 + threadIdx.x;
    int stride = gridDim.x * 256;
    for (; gid < E; gid += stride) atomicAdd(&counts[dst[gid]], 1);
}

__global__ __launch_bounds__(256) void scan_sums(const int* __restrict__ counts,
                                                 int* __restrict__ bsums, int N) {
    __shared__ int sdata[256];
    int base = blockIdx.x * SCAN_CHUNK + threadIdx.x * 4;
    int t = 0;
    #pragma unroll
    for (int j = 0; j < 4; ++j) { int i = base + j; if (i < N) t += counts[i]; }
    sdata[threadIdx.x] = t; __syncthreads();
    for (int off = 128; off > 0; off >>= 1) {
        if (threadIdx.x < off) sdata[threadIdx.x] += sdata[threadIdx.x + off];
        __syncthreads();
    }
    if (threadIdx.x == 0) bsums[blockIdx.x] = sdata[0];
}

__global__ void scan_offsets(const int* __restrict__ bsums, int* __restrict__ boffs,
                             int nb, int* __restrict__ row_ptr, int N, int E) {
    if (threadIdx.x == 0 && blockIdx.x == 0) {
        int run = 0;
        for (int i = 0; i < nb; ++i) { boffs[i] = run; run += bsums[i]; }
        row_ptr[N] = E;
    }
}

__global__ __launch_bounds__(256) void scan_write(const int* __restrict__ counts,
                                                  const int* __restrict__ boffs,
                                                  int* __restrict__ row_ptr,
                                                  int* __restrict__ cursor, int N) {
    __shared__ int sdata[256];
    int base = blockIdx.x * SCAN_CHUNK + threadIdx.x * 4;
    int v[4]; int tsum = 0;
    #pragma unroll
    for (int j = 0; j < 4; ++j) {
        int i = base + j;
        v[j] = (i < N) ? counts[i] : 0;
        tsum += v[j];
    }
    sdata[threadIdx.x] = tsum; __syncthreads();
    for (int off = 1; off < 256; off <<= 1) {
        int t = (threadIdx.x >= off) ? sdata[threadIdx.x - off] : 0;
        __syncthreads();
        sdata[threadIdx.x] += t;
        __syncthreads();
    }
    int off0 = sdata[threadIdx.x] - tsum + boffs[blockIdx.x];
    #pragma unroll
    for (int j = 0; j < 4; ++j) {
        int i = base + j;
        if (i < N) { row_ptr[i] = off0; cursor[i] = off0; off0 += v[j]; }
    }
}

__global__ __launch_bounds__(256) void fill_kernel(const int* __restrict__ src,
                                                   const int* __restrict__ dst,
                                                   const float* __restrict__ w,
                                                   int* __restrict__ cursor,
                                                   int* __restrict__ src_s,
                                                   float* __restrict__ w_s, int E) {
    int gid = blockIdx.x * 256 + threadIdx.x;
    int stride = gridDim.x * 256;
    for (; gid < E; gid += stride) {
        int d = dst[gid];
        int pos = atomicAdd(&cursor[d], 1);
        src_s[pos] = src[gid];
        w_s[pos]   = w[gid];
    }
}

__global__ void bn_prep(const float* __restrict__ b1, const float* __restrict__ gamma,
                        const float* __restrict__ beta, const float* __restrict__ mean,
                        const float* __restrict__ var, float* __restrict__ scale,
                        float* __restrict__ shift) {
    int f = threadIdx.x;
    if (f < HID) {
        float sc = gamma[f] * rsqrtf(var[f] + BN_EPS);
        scale[f] = sc;
        shift[f] = beta[f] + sc * (b1[f] - mean[f]);
    }
}

// ---------------------------------------------------------------------------
// Gather layer 1 (D=128): one wave per dst row, float2 per lane, shuffle
// broadcast of edge metadata. Fused BN+ReLU. No LDS, no barriers, no atomics.
// ---------------------------------------------------------------------------
__global__ __launch_bounds__(256) void gather1_kernel(
        const float* __restrict__ XW, const int* __restrict__ row_ptr,
        const int* __restrict__ src_s, const float* __restrict__ w_s,
        const float* __restrict__ scale, const float* __restrict__ shift,
        float* __restrict__ H, int N) {
    int r = blockIdx.x * 4 + (threadIdx.x >> 6);
    if (r >= N) return;                     // wave-uniform
    int f = threadIdx.x & 63;               // float2 index: cols 2f, 2f+1
    int beg = row_ptr[r], end = row_ptr[r + 1];
    float accx = 0.f, accy = 0.f;
    for (int base = beg; base < end; base += 64) {
        int m = end - base; if (m > 64) m = 64;
        int   se = (f < m) ? src_s[base + f] : 0;
        float we = (f < m) ? w_s[base + f] : 0.f;
        for (int k = 0; k < m; ++k) {
            int   sk = __shfl(se, k, 64);
            float wk = __shfl(we, k, 64);
            float2 x = *(const float2*)&XW[(size_t)sk * HID + 2 * f];
            accx = fmaf(x.x, wk, accx);
            accy = fmaf(x.y, wk, accy);
        }
    }
    float2 sc = *(const float2*)&scale[2 * f];
    float2 sh = *(const float2*)&shift[2 * f];
    float hx = fmaf(accx, sc.x, sh.x);
    float hy = fmaf(accy, sc.y, sh.y);
    float2 out;
    out.x = hx > 0.f ? hx : 0.f;
    out.y = hy > 0.f ? hy : 0.f;
    *(float2*)&H[(size_t)r * HID + 2 * f] = out;
}

// ---------------------------------------------------------------------------
// Gather layer 2 (D=64) + epilogue: one wave per dst row.
// ---------------------------------------------------------------------------
__global__ __launch_bounds__(256) void gather2_final(
        const float* __restrict__ XW2, const int* __restrict__ row_ptr,
        const int* __restrict__ src_s, const float* __restrict__ w_s,
        const float* __restrict__ b2, const float* __restrict__ prev,
        const int* __restrict__ sens, const int* __restrict__ ins,
        float* __restrict__ out_lsm, float* __restrict__ out_emb, int N) {
    int r = blockIdx.x * 4 + (threadIdx.x >> 6);
    if (r >= N) return;                     // wave-uniform
    int f = threadIdx.x & 63;
    int beg = row_ptr[r], end = row_ptr[r + 1];
    float acc = 0.f;
    for (int base = beg; base < end; base += 64) {
        int m = end - base; if (m > 64) m = 64;
        int   se = (f < m) ? src_s[base + f] : 0;
        float we = (f < m) ? w_s[base + f] : 0.f;
        for (int k = 0; k < m; ++k) {
            int   sk = __shfl(se, k, 64);
            float wk = __shfl(we, k, 64);
            acc = fmaf(XW2[(size_t)sk * CDIM + f], wk, acc);
        }
    }
    float h = acc + b2[f];
    bool s_ = sens[r] != 0;
    bool i_ = ins[r] != 0;
    float o = (s_ ? h : prev[(size_t)r * CDIM + f]) + (i_ ? h : 0.f);
    float m = o;
    #pragma unroll
    for (int off = 32; off > 0; off >>= 1) m = fmaxf(m, __shfl_xor(m, off, 64));
    float e = expf(o - m);
    float sum = e;
    #pragma unroll
    for (int off = 32; off > 0; off >>= 1) sum += __shfl_xor(sum, off, 64);
    out_lsm[(size_t)r * CDIM + f] = o - m - logf(sum);
    out_emb[(size_t)r * CDIM + f] = o;
}

extern "C" void kernel_launch(void* const* d_in, const int* in_sizes, int n_in,
                              void* d_out, int out_size, void* d_ws, size_t ws_size,
                              hipStream_t stream) {
    const float* features = (const float*)d_in[0];
    const int*   esrc     = (const int*)d_in[1];
    const int*   edst     = (const int*)d_in[2];
    const float* ew       = (const float*)d_in[3];
    const float* W1       = (const float*)d_in[4];
    const float* b1       = (const float*)d_in[5];
    const float* gamma1   = (const float*)d_in[6];
    const float* beta1    = (const float*)d_in[7];
    const float* mean1    = (const float*)d_in[8];
    const float* var1     = (const float*)d_in[9];
    const float* W2       = (const float*)d_in[10];
    const float* b2       = (const float*)d_in[11];
    const float* prev     = (const float*)d_in[12];
    const int*   sens     = (const int*)d_in[13];
    const int*   ins      = (const int*)d_in[14];

    const int N = in_sizes[0] / F_IN;
    const int E = in_sizes[1];
    const int nb = (N + SCAN_CHUNK - 1) / SCAN_CHUNK;

    // ---- workspace layout (fp32 words) ----
    float* xw1   = (float*)d_ws;                 // N*128  (reused as xw2: N*64)
    float* h     = xw1 + (size_t)N * HID;        // N*128
    float* scale = h + (size_t)N * HID;          // 128
    float* shift = scale + HID;                  // 128
    int* row_ptr = (int*)(shift + HID);          // N+1
    int* cursor  = row_ptr + (N + 1);            // N   (aliases counts)
    int* bsums   = cursor + N;                   // nb
    int* boffs   = bsums + nb;                   // nb
    int* src_s   = boffs + nb;                   // E
    float* w_s   = (float*)(src_s + E);          // E
    float* xw2   = xw1;                          // alias: xw1 dead after gather1

    float* out_lsm = (float*)d_out;
    float* out_emb = out_lsm + (size_t)N * CDIM;

    // ---- CSR build ----
    hipMemsetAsync(cursor, 0, (size_t)N * sizeof(int), stream);
    hist_kernel<<<(E + 255) / 256, 256, 0, stream>>>(edst, cursor, E);
    scan_sums<<<nb, 256, 0, stream>>>(cursor, bsums, N);
    scan_offsets<<<1, 64, 0, stream>>>(bsums, boffs, nb, row_ptr, N, E);
    scan_write<<<nb, 256, 0, stream>>>(cursor, boffs, row_ptr, cursor, N);
    fill_kernel<<<(E + 255) / 256, 256, 0, stream>>>(esrc, edst, ew, cursor,
                                                     src_s, w_s, E);
    bn_prep<<<1, 128, 0, stream>>>(b1, gamma1, beta1, mean1, var1, scale, shift);

    // ---- layer 1 ----
    const int ntiles = (N + 127) / 128;
    gemm_xw1<<<ntiles, 256, 0, stream>>>(features, W1, xw1, N);
    gather1_kernel<<<(N + 3) / 4, 256, 0, stream>>>(xw1, row_ptr, src_s, w_s,
                                                    scale, shift, h, N);
    // ---- layer 2 ----
    gemm_xw2<<<ntiles, 256, 0, stream>>>(h, W2, xw2, N);
    gather2_final<<<(N + 3) / 4, 256, 0, stream>>>(xw2, row_ptr, src_s, w_s,
                                                   b2, prev, sens, ins,
                                                   out_lsm, out_emb, N);
}

// Round 4
// 616.365 us; speedup vs baseline: 2.4778x; 1.1031x over previous
//
#include <hip/hip_runtime.h>
#include <math.h>

#define F_IN 128
#define HID  128
#define CDIM 64
#define BN_EPS 1e-5f
#define SCAN_CHUNK 1024   // elements per scan block (256 thr x 4)

typedef unsigned int u32;
typedef unsigned short u16;

// bf16 helpers (RNE), manual to avoid header variance
__device__ __forceinline__ float bf_lo(u32 p) {
    u32 x = p << 16; return __builtin_bit_cast(float, x);
}
__device__ __forceinline__ float bf_hi(u32 p) {
    u32 x = p & 0xffff0000u; return __builtin_bit_cast(float, x);
}
__device__ __forceinline__ u16 f2bf(float f) {
    u32 x = __builtin_bit_cast(u32, f);
    return (u16)((x + 0x7fffu + ((x >> 16) & 1u)) >> 16);
}
__device__ __forceinline__ u32 pack2(float a, float b) {
    return (u32)f2bf(a) | ((u32)f2bf(b) << 16);   // lo = even col
}

// ---------------------------------------------------------------------------
// GEMM1: Y[N,128](bf16) = X[N,128](fp32) @ W[128,128](fp32).
// 128x128 tile, K chunked by 64, 8x8 micro-tile, fp32 accumulate.
// ---------------------------------------------------------------------------
__global__ __launch_bounds__(256) void gemm_xw1(const float* __restrict__ X,
                                                const float* __restrict__ W,
                                                u32* __restrict__ Yb, int N) {
    __shared__ float Wl[64][128];    // 32 KB
    __shared__ float xs[128][64];    // 32 KB
    const int cg = (threadIdx.x & 15) * 8;
    const int rg = (threadIdx.x >> 4) * 8;
    const int ntiles = (N + 127) >> 7;
    for (int tile = blockIdx.x; tile < ntiles; tile += gridDim.x) {
        const int row0 = tile << 7;
        float acc[8][8];
        #pragma unroll
        for (int i = 0; i < 8; ++i)
            #pragma unroll
            for (int j = 0; j < 8; ++j) acc[i][j] = 0.f;

        for (int kc = 0; kc < 128; kc += 64) {
            __syncthreads();
            for (int i = threadIdx.x; i < 2048; i += 256) {
                int kr = i >> 5, c = (i & 31) * 4;
                *(float4*)&Wl[kr][c] = *(const float4*)&W[(size_t)(kc + kr) * HID + c];
            }
            for (int i = threadIdx.x; i < 2048; i += 256) {
                int r = i >> 4, c = (i & 15) * 4;
                int gr = row0 + r;
                float4 v = make_float4(0.f, 0.f, 0.f, 0.f);
                if (gr < N) v = *(const float4*)&X[(size_t)gr * F_IN + kc + c];
                *(float4*)&xs[r][c] = v;
            }
            __syncthreads();
            #pragma unroll 2
            for (int k = 0; k < 64; k += 2) {
                float2 a[8];
                #pragma unroll
                for (int i = 0; i < 8; ++i) a[i] = *(float2*)&xs[rg + i][k];
                float4 b00 = *(float4*)&Wl[k][cg];
                float4 b01 = *(float4*)&Wl[k][cg + 4];
                float4 b10 = *(float4*)&Wl[k + 1][cg];
                float4 b11 = *(float4*)&Wl[k + 1][cg + 4];
                #pragma unroll
                for (int i = 0; i < 8; ++i) {
                    acc[i][0] = fmaf(a[i].x, b00.x, acc[i][0]);
                    acc[i][1] = fmaf(a[i].x, b00.y, acc[i][1]);
                    acc[i][2] = fmaf(a[i].x, b00.z, acc[i][2]);
                    acc[i][3] = fmaf(a[i].x, b00.w, acc[i][3]);
                    acc[i][4] = fmaf(a[i].x, b01.x, acc[i][4]);
                    acc[i][5] = fmaf(a[i].x, b01.y, acc[i][5]);
                    acc[i][6] = fmaf(a[i].x, b01.z, acc[i][6]);
                    acc[i][7] = fmaf(a[i].x, b01.w, acc[i][7]);
                    acc[i][0] = fmaf(a[i].y, b10.x, acc[i][0]);
                    acc[i][1] = fmaf(a[i].y, b10.y, acc[i][1]);
                    acc[i][2] = fmaf(a[i].y, b10.z, acc[i][2]);
                    acc[i][3] = fmaf(a[i].y, b10.w, acc[i][3]);
                    acc[i][4] = fmaf(a[i].y, b11.x, acc[i][4]);
                    acc[i][5] = fmaf(a[i].y, b11.y, acc[i][5]);
                    acc[i][6] = fmaf(a[i].y, b11.z, acc[i][6]);
                    acc[i][7] = fmaf(a[i].y, b11.w, acc[i][7]);
                }
            }
        }
        #pragma unroll
        for (int i = 0; i < 8; ++i) {
            int gr = row0 + rg + i;
            if (gr < N) {
                uint4 o;
                o.x = pack2(acc[i][0], acc[i][1]);
                o.y = pack2(acc[i][2], acc[i][3]);
                o.z = pack2(acc[i][4], acc[i][5]);
                o.w = pack2(acc[i][6], acc[i][7]);
                *(uint4*)&Yb[(size_t)gr * 64 + (cg >> 1)] = o;
            }
        }
    }
}

// ---------------------------------------------------------------------------
// GEMM2: Y[N,64](bf16) = H[N,128](bf16) @ W[128,64](fp32).
// 128x64 tile, K chunked by 64, 8x4 micro-tile, fp32 accumulate.
// ---------------------------------------------------------------------------
__global__ __launch_bounds__(256) void gemm_xw2(const u32* __restrict__ Hb,
                                                const float* __restrict__ W,
                                                u32* __restrict__ Yb, int N) {
    __shared__ float Wl[64][64];     // 16 KB
    __shared__ float xs[128][64];    // 32 KB
    const int cg = (threadIdx.x & 15) * 4;
    const int rg = (threadIdx.x >> 4) * 8;
    const int ntiles = (N + 127) >> 7;
    for (int tile = blockIdx.x; tile < ntiles; tile += gridDim.x) {
        const int row0 = tile << 7;
        float acc[8][4];
        #pragma unroll
        for (int i = 0; i < 8; ++i)
            #pragma unroll
            for (int j = 0; j < 4; ++j) acc[i][j] = 0.f;

        for (int kc = 0; kc < 128; kc += 64) {
            __syncthreads();
            for (int i = threadIdx.x; i < 1024; i += 256) {          // W chunk
                int kr = i >> 4, c = (i & 15) * 4;
                *(float4*)&Wl[kr][c] = *(const float4*)&W[(size_t)(kc + kr) * CDIM + c];
            }
            // H chunk: 128 rows x 32 uints (64 bf16 cols); uint2 per item
            for (int i = threadIdx.x; i < 2048; i += 256) {
                int r = i >> 4, uc = (i & 15) * 2;      // uint-pair col
                int gr = row0 + r;
                float4 v = make_float4(0.f, 0.f, 0.f, 0.f);
                if (gr < N) {
                    uint2 p = *(const uint2*)&Hb[(size_t)gr * 64 + (kc >> 1) + uc];
                    v = make_float4(bf_lo(p.x), bf_hi(p.x), bf_lo(p.y), bf_hi(p.y));
                }
                *(float4*)&xs[r][uc * 2] = v;
            }
            __syncthreads();
            #pragma unroll 2
            for (int k = 0; k < 64; k += 2) {
                float2 a[8];
                #pragma unroll
                for (int i = 0; i < 8; ++i) a[i] = *(float2*)&xs[rg + i][k];
                float4 b0 = *(float4*)&Wl[k][cg];
                float4 b1 = *(float4*)&Wl[k + 1][cg];
                #pragma unroll
                for (int i = 0; i < 8; ++i) {
                    acc[i][0] = fmaf(a[i].x, b0.x, acc[i][0]);
                    acc[i][1] = fmaf(a[i].x, b0.y, acc[i][1]);
                    acc[i][2] = fmaf(a[i].x, b0.z, acc[i][2]);
                    acc[i][3] = fmaf(a[i].x, b0.w, acc[i][3]);
                    acc[i][0] = fmaf(a[i].y, b1.x, acc[i][0]);
                    acc[i][1] = fmaf(a[i].y, b1.y, acc[i][1]);
                    acc[i][2] = fmaf(a[i].y, b1.z, acc[i][2]);
                    acc[i][3] = fmaf(a[i].y, b1.w, acc[i][3]);
                }
            }
        }
        #pragma unroll
        for (int i = 0; i < 8; ++i) {
            int gr = row0 + rg + i;
            if (gr < N) {
                uint2 o;
                o.x = pack2(acc[i][0], acc[i][1]);
                o.y = pack2(acc[i][2], acc[i][3]);
                *(uint2*)&Yb[(size_t)gr * 32 + (cg >> 1)] = o;
            }
        }
    }
}

// ---------------------------------------------------------------------------
// CSR build: histogram -> scan -> fill (shared by both layers)
// ---------------------------------------------------------------------------
__global__ __launch_bounds__(256) void hist_kernel(const int* __restrict__ dst,
                                                   int* __restrict__ counts, int E) {
    int gid = blockIdx.x * 256 + threadIdx.x;
    int stride = gridDim.x * 256;
    for (; gid < E; gid += stride) atomicAdd(&counts[dst[gid]], 1);
}

__global__ __launch_bounds__(256) void scan_sums(const int* __restrict__ counts,
                                                 int* __restrict__ bsums, int N) {
    __shared__ int sdata[256];
    int base = blockIdx.x * SCAN_CHUNK + threadIdx.x * 4;
    int t = 0;
    #pragma unroll
    for (int j = 0; j < 4; ++j) { int i = base + j; if (i < N) t += counts[i]; }
    sdata[threadIdx.x] = t; __syncthreads();
    for (int off = 128; off > 0; off >>= 1) {
        if (threadIdx.x < off) sdata[threadIdx.x] += sdata[threadIdx.x + off];
        __syncthreads();
    }
    if (threadIdx.x == 0) bsums[blockIdx.x] = sdata[0];
}

__global__ void scan_offsets(const int* __restrict__ bsums, int* __restrict__ boffs,
                             int nb, int* __restrict__ row_ptr, int N, int E) {
    if (threadIdx.x == 0 && blockIdx.x == 0) {
        int run = 0;
        for (int i = 0; i < nb; ++i) { boffs[i] = run; run += bsums[i]; }
        row_ptr[N] = E;
    }
}

__global__ __launch_bounds__(256) void scan_write(const int* __restrict__ counts,
                                                  const int* __restrict__ boffs,
                                                  int* __restrict__ row_ptr,
                                                  int* __restrict__ cursor, int N) {
    __shared__ int sdata[256];
    int base = blockIdx.x * SCAN_CHUNK + threadIdx.x * 4;
    int v[4]; int tsum = 0;
    #pragma unroll
    for (int j = 0; j < 4; ++j) {
        int i = base + j;
        v[j] = (i < N) ? counts[i] : 0;
        tsum += v[j];
    }
    sdata[threadIdx.x] = tsum; __syncthreads();
    for (int off = 1; off < 256; off <<= 1) {
        int t = (threadIdx.x >= off) ? sdata[threadIdx.x - off] : 0;
        __syncthreads();
        sdata[threadIdx.x] += t;
        __syncthreads();
    }
    int off0 = sdata[threadIdx.x] - tsum + boffs[blockIdx.x];
    #pragma unroll
    for (int j = 0; j < 4; ++j) {
        int i = base + j;
        if (i < N) { row_ptr[i] = off0; cursor[i] = off0; off0 += v[j]; }
    }
}

__global__ __launch_bounds__(256) void fill_kernel(const int* __restrict__ src,
                                                   const int* __restrict__ dst,
                                                   const float* __restrict__ w,
                                                   int* __restrict__ cursor,
                                                   int* __restrict__ src_s,
                                                   float* __restrict__ w_s, int E) {
    int gid = blockIdx.x * 256 + threadIdx.x;
    int stride = gridDim.x * 256;
    for (; gid < E; gid += stride) {
        int d = dst[gid];
        int pos = atomicAdd(&cursor[d], 1);
        src_s[pos] = src[gid];
        w_s[pos]   = w[gid];
    }
}

__global__ void bn_prep(const float* __restrict__ b1, const float* __restrict__ gamma,
                        const float* __restrict__ beta, const float* __restrict__ mean,
                        const float* __restrict__ var, float* __restrict__ scale,
                        float* __restrict__ shift) {
    int f = threadIdx.x;
    if (f < HID) {
        float sc = gamma[f] * rsqrtf(var[f] + BN_EPS);
        scale[f] = sc;
        shift[f] = beta[f] + sc * (b1[f] - mean[f]);
    }
}

// ---------------------------------------------------------------------------
// Gather layer 1 (D=128, bf16 in/out): one wave per dst row; lane f holds
// cols 2f,2f+1 (one packed u32 load = 4 B/lane, 256 B/edge). Fused BN+ReLU.
// ---------------------------------------------------------------------------
__global__ __launch_bounds__(256) void gather1_kernel(
        const u32* __restrict__ XWb, const int* __restrict__ row_ptr,
        const int* __restrict__ src_s, const float* __restrict__ w_s,
        const float* __restrict__ scale, const float* __restrict__ shift,
        u32* __restrict__ Hb, int N) {
    int r = blockIdx.x * 4 + (threadIdx.x >> 6);
    if (r >= N) return;                     // wave-uniform
    int f = threadIdx.x & 63;
    int beg = row_ptr[r], end = row_ptr[r + 1];
    float accx = 0.f, accy = 0.f;
    for (int base = beg; base < end; base += 64) {
        int m = end - base; if (m > 64) m = 64;
        int   se = (f < m) ? src_s[base + f] : 0;
        float we = (f < m) ? w_s[base + f] : 0.f;
        for (int k = 0; k < m; ++k) {
            int   sk = __shfl(se, k, 64);
            float wk = __shfl(we, k, 64);
            u32 x = XWb[(size_t)sk * 64 + f];
            accx = fmaf(bf_lo(x), wk, accx);
            accy = fmaf(bf_hi(x), wk, accy);
        }
    }
    float2 sc = *(const float2*)&scale[2 * f];
    float2 sh = *(const float2*)&shift[2 * f];
    float hx = fmaf(accx, sc.x, sh.x);
    float hy = fmaf(accy, sc.y, sh.y);
    hx = hx > 0.f ? hx : 0.f;
    hy = hy > 0.f ? hy : 0.f;
    Hb[(size_t)r * 64 + f] = pack2(hx, hy);
}

// ---------------------------------------------------------------------------
// Gather layer 2 (D=64, bf16 in) + epilogue: one wave per dst row,
// TWO edges per iteration (lanes 0-31 edge k, lanes 32-63 edge k+1; each
// half-lane holds cols 2fc,2fc+1). Halves merged via shfl_xor(32).
// ---------------------------------------------------------------------------
__global__ __launch_bounds__(256) void gather2_final(
        const u32* __restrict__ XW2b, const int* __restrict__ row_ptr,
        const int* __restrict__ src_s, const float* __restrict__ w_s,
        const float* __restrict__ b2, const float* __restrict__ prev,
        const int* __restrict__ sens, const int* __restrict__ ins,
        float* __restrict__ out_lsm, float* __restrict__ out_emb, int N) {
    int r = blockIdx.x * 4 + (threadIdx.x >> 6);
    if (r >= N) return;                     // wave-uniform
    int f = threadIdx.x & 63;
    int half = f >> 5;                      // which edge of the pair
    int fc = f & 31;                        // col-pair index (cols 2fc, 2fc+1)
    int beg = row_ptr[r], end = row_ptr[r + 1];
    float accx = 0.f, accy = 0.f;
    for (int base = beg; base < end; base += 64) {
        int m = end - base; if (m > 64) m = 64;
        int   se = (f < m) ? src_s[base + f] : 0;
        float we = (f < m) ? w_s[base + f] : 0.f;
        for (int k = 0; k < m; k += 2) {
            int k0 = k + half;              // <= 63 always; we==0 beyond m
            int   sk = __shfl(se, k0, 64);
            float wk = __shfl(we, k0, 64);
            u32 x = XW2b[(size_t)sk * 32 + fc];
            accx = fmaf(bf_lo(x), wk, accx);
            accy = fmaf(bf_hi(x), wk, accy);
        }
    }
    // merge the two half-wave partial sums; both halves end up identical
    accx += __shfl_xor(accx, 32, 64);
    accy += __shfl_xor(accy, 32, 64);

    float2 bb = *(const float2*)&b2[2 * fc];
    float hx = accx + bb.x, hy = accy + bb.y;
    bool s_ = sens[r] != 0;
    bool i_ = ins[r] != 0;
    float2 pv = *(const float2*)&prev[(size_t)r * CDIM + 2 * fc];
    float ox = (s_ ? hx : pv.x) + (i_ ? hx : 0.f);
    float oy = (s_ ? hy : pv.y) + (i_ ? hy : 0.f);
    // 64-col log-softmax over 32-lane groups (2 cols/lane; halves identical)
    float mm = fmaxf(ox, oy);
    #pragma unroll
    for (int off = 16; off > 0; off >>= 1) mm = fmaxf(mm, __shfl_xor(mm, off, 64));
    float s = expf(ox - mm) + expf(oy - mm);
    #pragma unroll
    for (int off = 16; off > 0; off >>= 1) s += __shfl_xor(s, off, 64);
    float lse = mm + logf(s);
    if (half == 0) {
        *(float2*)&out_lsm[(size_t)r * CDIM + 2 * fc] = make_float2(ox - lse, oy - lse);
        *(float2*)&out_emb[(size_t)r * CDIM + 2 * fc] = make_float2(ox, oy);
    }
}

extern "C" void kernel_launch(void* const* d_in, const int* in_sizes, int n_in,
                              void* d_out, int out_size, void* d_ws, size_t ws_size,
                              hipStream_t stream) {
    const float* features = (const float*)d_in[0];
    const int*   esrc     = (const int*)d_in[1];
    const int*   edst     = (const int*)d_in[2];
    const float* ew       = (const float*)d_in[3];
    const float* W1       = (const float*)d_in[4];
    const float* b1       = (const float*)d_in[5];
    const float* gamma1   = (const float*)d_in[6];
    const float* beta1    = (const float*)d_in[7];
    const float* mean1    = (const float*)d_in[8];
    const float* var1     = (const float*)d_in[9];
    const float* W2       = (const float*)d_in[10];
    const float* b2       = (const float*)d_in[11];
    const float* prev     = (const float*)d_in[12];
    const int*   sens     = (const int*)d_in[13];
    const int*   ins      = (const int*)d_in[14];

    const int N = in_sizes[0] / F_IN;
    const int E = in_sizes[1];
    const int nb = (N + SCAN_CHUNK - 1) / SCAN_CHUNK;

    // ---- workspace layout (u32 words) ----
    u32* xw1b  = (u32*)d_ws;                     // N*64  (128 bf16 cols)
    u32* hb    = xw1b + (size_t)N * 64;          // N*64
    u32* xw2b  = hb + (size_t)N * 64;            // N*32  (64 bf16 cols)
    float* scale = (float*)(xw2b + (size_t)N * 32);  // 128
    float* shift = scale + HID;                  // 128
    int* row_ptr = (int*)(shift + HID);          // N+1
    int* cursor  = row_ptr + (N + 1);            // N   (aliases counts)
    int* bsums   = cursor + N;                   // nb
    int* boffs   = bsums + nb;                   // nb
    int* src_s   = boffs + nb;                   // E
    float* w_s   = (float*)(src_s + E);          // E

    float* out_lsm = (float*)d_out;
    float* out_emb = out_lsm + (size_t)N * CDIM;

    // ---- CSR build ----
    hipMemsetAsync(cursor, 0, (size_t)N * sizeof(int), stream);
    hist_kernel<<<(E + 255) / 256, 256, 0, stream>>>(edst, cursor, E);
    scan_sums<<<nb, 256, 0, stream>>>(cursor, bsums, N);
    scan_offsets<<<1, 64, 0, stream>>>(bsums, boffs, nb, row_ptr, N, E);
    scan_write<<<nb, 256, 0, stream>>>(cursor, boffs, row_ptr, cursor, N);
    fill_kernel<<<(E + 255) / 256, 256, 0, stream>>>(esrc, edst, ew, cursor,
                                                     src_s, w_s, E);
    bn_prep<<<1, 128, 0, stream>>>(b1, gamma1, beta1, mean1, var1, scale, shift);

    // ---- layer 1 ----
    const int ntiles = (N + 127) / 128;
    gemm_xw1<<<ntiles, 256, 0, stream>>>(features, W1, xw1b, N);
    gather1_kernel<<<(N + 3) / 4, 256, 0, stream>>>(xw1b, row_ptr, src_s, w_s,
                                                    scale, shift, hb, N);
    // ---- layer 2 ----
    gemm_xw2<<<ntiles, 256, 0, stream>>>(hb, W2, xw2b, N);
    gather2_final<<<(N + 3) / 4, 256, 0, stream>>>(xw2b, row_ptr, src_s, w_s,
                                                   b2, prev, sens, ins,
                                                   out_lsm, out_emb, N);
}

// Round 5
// 534.856 us; speedup vs baseline: 2.8554x; 1.1524x over previous
//
#include <hip/hip_runtime.h>
#include <math.h>

#define F_IN 128
#define HID  128
#define CDIM 64
#define BN_EPS 1e-5f
#define SCAN_CHUNK 1024   // elements per scan block (256 thr x 4)

typedef unsigned int u32;
typedef unsigned short u16;

// bf16 helpers (RNE)
__device__ __forceinline__ float bf_lo(u32 p) {
    u32 x = p << 16; return __builtin_bit_cast(float, x);
}
__device__ __forceinline__ float bf_hi(u32 p) {
    u32 x = p & 0xffff0000u; return __builtin_bit_cast(float, x);
}
__device__ __forceinline__ u16 f2bf(float f) {
    u32 x = __builtin_bit_cast(u32, f);
    return (u16)((x + 0x7fffu + ((x >> 16) & 1u)) >> 16);
}
__device__ __forceinline__ u32 pack2(float a, float b) {
    return (u32)f2bf(a) | ((u32)f2bf(b) << 16);   // lo = even col
}

// ---------------------------------------------------------------------------
// GEMM1: Y[N,128](bf16) = X[N,128](fp32) @ W[128,128](fp32).
// ---------------------------------------------------------------------------
__global__ __launch_bounds__(256) void gemm_xw1(const float* __restrict__ X,
                                                const float* __restrict__ W,
                                                u32* __restrict__ Yb, int N) {
    __shared__ float Wl[64][128];    // 32 KB
    __shared__ float xs[128][64];    // 32 KB
    const int cg = (threadIdx.x & 15) * 8;
    const int rg = (threadIdx.x >> 4) * 8;
    const int ntiles = (N + 127) >> 7;
    for (int tile = blockIdx.x; tile < ntiles; tile += gridDim.x) {
        const int row0 = tile << 7;
        float acc[8][8];
        #pragma unroll
        for (int i = 0; i < 8; ++i)
            #pragma unroll
            for (int j = 0; j < 8; ++j) acc[i][j] = 0.f;

        for (int kc = 0; kc < 128; kc += 64) {
            __syncthreads();
            for (int i = threadIdx.x; i < 2048; i += 256) {
                int kr = i >> 5, c = (i & 31) * 4;
                *(float4*)&Wl[kr][c] = *(const float4*)&W[(size_t)(kc + kr) * HID + c];
            }
            for (int i = threadIdx.x; i < 2048; i += 256) {
                int r = i >> 4, c = (i & 15) * 4;
                int gr = row0 + r;
                float4 v = make_float4(0.f, 0.f, 0.f, 0.f);
                if (gr < N) v = *(const float4*)&X[(size_t)gr * F_IN + kc + c];
                *(float4*)&xs[r][c] = v;
            }
            __syncthreads();
            #pragma unroll 2
            for (int k = 0; k < 64; k += 2) {
                float2 a[8];
                #pragma unroll
                for (int i = 0; i < 8; ++i) a[i] = *(float2*)&xs[rg + i][k];
                float4 b00 = *(float4*)&Wl[k][cg];
                float4 b01 = *(float4*)&Wl[k][cg + 4];
                float4 b10 = *(float4*)&Wl[k + 1][cg];
                float4 b11 = *(float4*)&Wl[k + 1][cg + 4];
                #pragma unroll
                for (int i = 0; i < 8; ++i) {
                    acc[i][0] = fmaf(a[i].x, b00.x, acc[i][0]);
                    acc[i][1] = fmaf(a[i].x, b00.y, acc[i][1]);
                    acc[i][2] = fmaf(a[i].x, b00.z, acc[i][2]);
                    acc[i][3] = fmaf(a[i].x, b00.w, acc[i][3]);
                    acc[i][4] = fmaf(a[i].x, b01.x, acc[i][4]);
                    acc[i][5] = fmaf(a[i].x, b01.y, acc[i][5]);
                    acc[i][6] = fmaf(a[i].x, b01.z, acc[i][6]);
                    acc[i][7] = fmaf(a[i].x, b01.w, acc[i][7]);
                    acc[i][0] = fmaf(a[i].y, b10.x, acc[i][0]);
                    acc[i][1] = fmaf(a[i].y, b10.y, acc[i][1]);
                    acc[i][2] = fmaf(a[i].y, b10.z, acc[i][2]);
                    acc[i][3] = fmaf(a[i].y, b10.w, acc[i][3]);
                    acc[i][4] = fmaf(a[i].y, b11.x, acc[i][4]);
                    acc[i][5] = fmaf(a[i].y, b11.y, acc[i][5]);
                    acc[i][6] = fmaf(a[i].y, b11.z, acc[i][6]);
                    acc[i][7] = fmaf(a[i].y, b11.w, acc[i][7]);
                }
            }
        }
        #pragma unroll
        for (int i = 0; i < 8; ++i) {
            int gr = row0 + rg + i;
            if (gr < N) {
                uint4 o;
                o.x = pack2(acc[i][0], acc[i][1]);
                o.y = pack2(acc[i][2], acc[i][3]);
                o.z = pack2(acc[i][4], acc[i][5]);
                o.w = pack2(acc[i][6], acc[i][7]);
                *(uint4*)&Yb[(size_t)gr * 64 + (cg >> 1)] = o;
            }
        }
    }
}

// ---------------------------------------------------------------------------
// GEMM2: Y[N,64](bf16) = H[N,128](bf16) @ W[128,64](fp32).
// ---------------------------------------------------------------------------
__global__ __launch_bounds__(256) void gemm_xw2(const u32* __restrict__ Hb,
                                                const float* __restrict__ W,
                                                u32* __restrict__ Yb, int N) {
    __shared__ float Wl[64][64];     // 16 KB
    __shared__ float xs[128][64];    // 32 KB
    const int cg = (threadIdx.x & 15) * 4;
    const int rg = (threadIdx.x >> 4) * 8;
    const int ntiles = (N + 127) >> 7;
    for (int tile = blockIdx.x; tile < ntiles; tile += gridDim.x) {
        const int row0 = tile << 7;
        float acc[8][4];
        #pragma unroll
        for (int i = 0; i < 8; ++i)
            #pragma unroll
            for (int j = 0; j < 4; ++j) acc[i][j] = 0.f;

        for (int kc = 0; kc < 128; kc += 64) {
            __syncthreads();
            for (int i = threadIdx.x; i < 1024; i += 256) {          // W chunk
                int kr = i >> 4, c = (i & 15) * 4;
                *(float4*)&Wl[kr][c] = *(const float4*)&W[(size_t)(kc + kr) * CDIM + c];
            }
            for (int i = threadIdx.x; i < 2048; i += 256) {          // H chunk
                int r = i >> 4, uc = (i & 15) * 2;
                int gr = row0 + r;
                float4 v = make_float4(0.f, 0.f, 0.f, 0.f);
                if (gr < N) {
                    uint2 p = *(const uint2*)&Hb[(size_t)gr * 64 + (kc >> 1) + uc];
                    v = make_float4(bf_lo(p.x), bf_hi(p.x), bf_lo(p.y), bf_hi(p.y));
                }
                *(float4*)&xs[r][uc * 2] = v;
            }
            __syncthreads();
            #pragma unroll 2
            for (int k = 0; k < 64; k += 2) {
                float2 a[8];
                #pragma unroll
                for (int i = 0; i < 8; ++i) a[i] = *(float2*)&xs[rg + i][k];
                float4 b0 = *(float4*)&Wl[k][cg];
                float4 b1 = *(float4*)&Wl[k + 1][cg];
                #pragma unroll
                for (int i = 0; i < 8; ++i) {
                    acc[i][0] = fmaf(a[i].x, b0.x, acc[i][0]);
                    acc[i][1] = fmaf(a[i].x, b0.y, acc[i][1]);
                    acc[i][2] = fmaf(a[i].x, b0.z, acc[i][2]);
                    acc[i][3] = fmaf(a[i].x, b0.w, acc[i][3]);
                    acc[i][0] = fmaf(a[i].y, b1.x, acc[i][0]);
                    acc[i][1] = fmaf(a[i].y, b1.y, acc[i][1]);
                    acc[i][2] = fmaf(a[i].y, b1.z, acc[i][2]);
                    acc[i][3] = fmaf(a[i].y, b1.w, acc[i][3]);
                }
            }
        }
        #pragma unroll
        for (int i = 0; i < 8; ++i) {
            int gr = row0 + rg + i;
            if (gr < N) {
                uint2 o;
                o.x = pack2(acc[i][0], acc[i][1]);
                o.y = pack2(acc[i][2], acc[i][3]);
                *(uint2*)&Yb[(size_t)gr * 32 + (cg >> 1)] = o;
            }
        }
    }
}

// ---------------------------------------------------------------------------
// CSR build: histogram -> scan -> fill
// ---------------------------------------------------------------------------
__global__ __launch_bounds__(256) void hist_kernel(const int* __restrict__ dst,
                                                   int* __restrict__ counts, int E) {
    int gid = blockIdx.x * 256 + threadIdx.x;
    int stride = gridDim.x * 256;
    for (; gid < E; gid += stride) atomicAdd(&counts[dst[gid]], 1);
}

__global__ __launch_bounds__(256) void scan_sums(const int* __restrict__ counts,
                                                 int* __restrict__ bsums, int N) {
    __shared__ int sdata[256];
    int base = blockIdx.x * SCAN_CHUNK + threadIdx.x * 4;
    int t = 0;
    #pragma unroll
    for (int j = 0; j < 4; ++j) { int i = base + j; if (i < N) t += counts[i]; }
    sdata[threadIdx.x] = t; __syncthreads();
    for (int off = 128; off > 0; off >>= 1) {
        if (threadIdx.x < off) sdata[threadIdx.x] += sdata[threadIdx.x + off];
        __syncthreads();
    }
    if (threadIdx.x == 0) bsums[blockIdx.x] = sdata[0];
}

__global__ void scan_offsets(const int* __restrict__ bsums, int* __restrict__ boffs,
                             int nb, int* __restrict__ row_ptr, int N, int E) {
    if (threadIdx.x == 0 && blockIdx.x == 0) {
        int run = 0;
        for (int i = 0; i < nb; ++i) { boffs[i] = run; run += bsums[i]; }
        row_ptr[N] = E;
    }
}

__global__ __launch_bounds__(256) void scan_write(const int* __restrict__ counts,
                                                  const int* __restrict__ boffs,
                                                  int* __restrict__ row_ptr,
                                                  int* __restrict__ cursor, int N) {
    __shared__ int sdata[256];
    int base = blockIdx.x * SCAN_CHUNK + threadIdx.x * 4;
    int v[4]; int tsum = 0;
    #pragma unroll
    for (int j = 0; j < 4; ++j) {
        int i = base + j;
        v[j] = (i < N) ? counts[i] : 0;
        tsum += v[j];
    }
    sdata[threadIdx.x] = tsum; __syncthreads();
    for (int off = 1; off < 256; off <<= 1) {
        int t = (threadIdx.x >= off) ? sdata[threadIdx.x - off] : 0;
        __syncthreads();
        sdata[threadIdx.x] += t;
        __syncthreads();
    }
    int off0 = sdata[threadIdx.x] - tsum + boffs[blockIdx.x];
    #pragma unroll
    for (int j = 0; j < 4; ++j) {
        int i = base + j;
        if (i < N) { row_ptr[i] = off0; cursor[i] = off0; off0 += v[j]; }
    }
}

// fill: single 8-byte packed store per edge {src, w_bits}
__global__ __launch_bounds__(256) void fill_kernel(const int* __restrict__ src,
                                                   const int* __restrict__ dst,
                                                   const float* __restrict__ w,
                                                   int* __restrict__ cursor,
                                                   uint2* __restrict__ es_packed, int E) {
    int gid = blockIdx.x * 256 + threadIdx.x;
    int stride = gridDim.x * 256;
    for (; gid < E; gid += stride) {
        int d = dst[gid];
        int pos = atomicAdd(&cursor[d], 1);
        uint2 pk;
        pk.x = (u32)src[gid];
        pk.y = __builtin_bit_cast(u32, w[gid]);
        es_packed[pos] = pk;
    }
}

__global__ void bn_prep(const float* __restrict__ b1, const float* __restrict__ gamma,
                        const float* __restrict__ beta, const float* __restrict__ mean,
                        const float* __restrict__ var, float* __restrict__ scale,
                        float* __restrict__ shift) {
    int f = threadIdx.x;
    if (f < HID) {
        float sc = gamma[f] * rsqrtf(var[f] + BN_EPS);
        scale[f] = sc;
        shift[f] = beta[f] + sc * (b1[f] - mean[f]);
    }
}

// ---------------------------------------------------------------------------
// Gather layer 1 (D=128 bf16): one wave per dst row, FOUR edges per
// iteration. Lane f = q*16+fc (q = edge-of-quad, fc = col-group); each lane
// loads uint4 = 8 bf16 cols of the q-th edge's source row. Partials merged
// with shfl_xor(16)+(32). Fused BN+ReLU epilogue; quarter 0 stores the row.
// ---------------------------------------------------------------------------
__global__ __launch_bounds__(256) void gather1_kernel(
        const u32* __restrict__ XWb, const int* __restrict__ row_ptr,
        const uint2* __restrict__ es, const float* __restrict__ scale,
        const float* __restrict__ shift, u32* __restrict__ Hb, int N) {
    int r = blockIdx.x * 4 + (threadIdx.x >> 6);
    if (r >= N) return;                     // wave-uniform
    int f = threadIdx.x & 63;
    int q = f >> 4;                         // edge within quad
    int fc = f & 15;                        // col group: bf16 cols 8fc..8fc+7
    int beg = row_ptr[r], end = row_ptr[r + 1];
    float acc[8];
    #pragma unroll
    for (int j = 0; j < 8; ++j) acc[j] = 0.f;
    for (int base = beg; base < end; base += 64) {
        int m = end - base; if (m > 64) m = 64;
        uint2 pk = (f < m) ? es[base + f] : make_uint2(0u, 0u);
        int   se = (int)pk.x;
        float we = __builtin_bit_cast(float, pk.y);
        for (int k = 0; k < m; k += 4) {
            int k0 = k + q;
            int   sk = __shfl(se, k0, 64);
            float wk = __shfl(we, k0, 64);
            uint4 x = *(const uint4*)&XWb[(size_t)sk * 64 + 4 * fc];
            acc[0] = fmaf(bf_lo(x.x), wk, acc[0]);
            acc[1] = fmaf(bf_hi(x.x), wk, acc[1]);
            acc[2] = fmaf(bf_lo(x.y), wk, acc[2]);
            acc[3] = fmaf(bf_hi(x.y), wk, acc[3]);
            acc[4] = fmaf(bf_lo(x.z), wk, acc[4]);
            acc[5] = fmaf(bf_hi(x.z), wk, acc[5]);
            acc[6] = fmaf(bf_lo(x.w), wk, acc[6]);
            acc[7] = fmaf(bf_hi(x.w), wk, acc[7]);
        }
    }
    #pragma unroll
    for (int j = 0; j < 8; ++j) {
        acc[j] += __shfl_xor(acc[j], 16, 64);
        acc[j] += __shfl_xor(acc[j], 32, 64);
    }
    if (q == 0) {
        float4 sc0 = *(const float4*)&scale[8 * fc];
        float4 sc1 = *(const float4*)&scale[8 * fc + 4];
        float4 sh0 = *(const float4*)&shift[8 * fc];
        float4 sh1 = *(const float4*)&shift[8 * fc + 4];
        float h0 = fmaf(acc[0], sc0.x, sh0.x);
        float h1 = fmaf(acc[1], sc0.y, sh0.y);
        float h2 = fmaf(acc[2], sc0.z, sh0.z);
        float h3 = fmaf(acc[3], sc0.w, sh0.w);
        float h4 = fmaf(acc[4], sc1.x, sh1.x);
        float h5 = fmaf(acc[5], sc1.y, sh1.y);
        float h6 = fmaf(acc[6], sc1.z, sh1.z);
        float h7 = fmaf(acc[7], sc1.w, sh1.w);
        uint4 o;
        o.x = pack2(h0 > 0.f ? h0 : 0.f, h1 > 0.f ? h1 : 0.f);
        o.y = pack2(h2 > 0.f ? h2 : 0.f, h3 > 0.f ? h3 : 0.f);
        o.z = pack2(h4 > 0.f ? h4 : 0.f, h5 > 0.f ? h5 : 0.f);
        o.w = pack2(h6 > 0.f ? h6 : 0.f, h7 > 0.f ? h7 : 0.f);
        *(uint4*)&Hb[(size_t)r * 64 + 4 * fc] = o;
    }
}

// ---------------------------------------------------------------------------
// Gather layer 2 (D=64 bf16) + epilogue: one wave per dst row, FOUR edges
// per iteration (16 lanes/edge, uint2 = 4 cols/lane). Quarter 0 writes.
// ---------------------------------------------------------------------------
__global__ __launch_bounds__(256) void gather2_final(
        const u32* __restrict__ XW2b, const int* __restrict__ row_ptr,
        const uint2* __restrict__ es, const float* __restrict__ b2,
        const float* __restrict__ prev, const int* __restrict__ sens,
        const int* __restrict__ ins, float* __restrict__ out_lsm,
        float* __restrict__ out_emb, int N) {
    int r = blockIdx.x * 4 + (threadIdx.x >> 6);
    if (r >= N) return;                     // wave-uniform
    int f = threadIdx.x & 63;
    int q = f >> 4;                         // edge within quad
    int fc = f & 15;                        // col group: bf16 cols 4fc..4fc+3
    int beg = row_ptr[r], end = row_ptr[r + 1];
    float a0 = 0.f, a1 = 0.f, a2 = 0.f, a3 = 0.f;
    for (int base = beg; base < end; base += 64) {
        int m = end - base; if (m > 64) m = 64;
        uint2 pk = (f < m) ? es[base + f] : make_uint2(0u, 0u);
        int   se = (int)pk.x;
        float we = __builtin_bit_cast(float, pk.y);
        for (int k = 0; k < m; k += 4) {
            int k0 = k + q;
            int   sk = __shfl(se, k0, 64);
            float wk = __shfl(we, k0, 64);
            uint2 x = *(const uint2*)&XW2b[(size_t)sk * 32 + 2 * fc];
            a0 = fmaf(bf_lo(x.x), wk, a0);
            a1 = fmaf(bf_hi(x.x), wk, a1);
            a2 = fmaf(bf_lo(x.y), wk, a2);
            a3 = fmaf(bf_hi(x.y), wk, a3);
        }
    }
    a0 += __shfl_xor(a0, 16, 64); a0 += __shfl_xor(a0, 32, 64);
    a1 += __shfl_xor(a1, 16, 64); a1 += __shfl_xor(a1, 32, 64);
    a2 += __shfl_xor(a2, 16, 64); a2 += __shfl_xor(a2, 32, 64);
    a3 += __shfl_xor(a3, 16, 64); a3 += __shfl_xor(a3, 32, 64);

    float4 bb = *(const float4*)&b2[4 * fc];
    float h0 = a0 + bb.x, h1 = a1 + bb.y, h2 = a2 + bb.z, h3 = a3 + bb.w;
    bool s_ = sens[r] != 0;
    bool i_ = ins[r] != 0;
    float4 pv = *(const float4*)&prev[(size_t)r * CDIM + 4 * fc];
    float o0 = (s_ ? h0 : pv.x) + (i_ ? h0 : 0.f);
    float o1 = (s_ ? h1 : pv.y) + (i_ ? h1 : 0.f);
    float o2 = (s_ ? h2 : pv.z) + (i_ ? h2 : 0.f);
    float o3 = (s_ ? h3 : pv.w) + (i_ ? h3 : 0.f);
    // log-softmax over 64 cols: local max/sum of 4, reduce over 16 lanes
    float mm = fmaxf(fmaxf(o0, o1), fmaxf(o2, o3));
    #pragma unroll
    for (int off = 8; off > 0; off >>= 1) mm = fmaxf(mm, __shfl_xor(mm, off, 64));
    float s = expf(o0 - mm) + expf(o1 - mm) + expf(o2 - mm) + expf(o3 - mm);
    #pragma unroll
    for (int off = 8; off > 0; off >>= 1) s += __shfl_xor(s, off, 64);
    float lse = mm + logf(s);
    if (q == 0) {
        *(float4*)&out_lsm[(size_t)r * CDIM + 4 * fc] =
            make_float4(o0 - lse, o1 - lse, o2 - lse, o3 - lse);
        *(float4*)&out_emb[(size_t)r * CDIM + 4 * fc] =
            make_float4(o0, o1, o2, o3);
    }
}

extern "C" void kernel_launch(void* const* d_in, const int* in_sizes, int n_in,
                              void* d_out, int out_size, void* d_ws, size_t ws_size,
                              hipStream_t stream) {
    const float* features = (const float*)d_in[0];
    const int*   esrc     = (const int*)d_in[1];
    const int*   edst     = (const int*)d_in[2];
    const float* ew       = (const float*)d_in[3];
    const float* W1       = (const float*)d_in[4];
    const float* b1       = (const float*)d_in[5];
    const float* gamma1   = (const float*)d_in[6];
    const float* beta1    = (const float*)d_in[7];
    const float* mean1    = (const float*)d_in[8];
    const float* var1     = (const float*)d_in[9];
    const float* W2       = (const float*)d_in[10];
    const float* b2       = (const float*)d_in[11];
    const float* prev     = (const float*)d_in[12];
    const int*   sens     = (const int*)d_in[13];
    const int*   ins      = (const int*)d_in[14];

    const int N = in_sizes[0] / F_IN;
    const int E = in_sizes[1];
    const int nb = (N + SCAN_CHUNK - 1) / SCAN_CHUNK;

    // ---- workspace layout (u32 words); es_packed kept 8B-aligned ----
    u32* xw1b  = (u32*)d_ws;                         // N*64  (128 bf16 cols)
    u32* hb    = xw1b + (size_t)N * 64;              // N*64
    u32* xw2b  = hb + (size_t)N * 64;                // N*32
    uint2* es_packed = (uint2*)(xw2b + (size_t)N * 32);  // E x 8B (aligned: 160N even)
    float* scale = (float*)(es_packed + E);          // 128
    float* shift = scale + HID;                      // 128
    int* row_ptr = (int*)(shift + HID);              // N+1
    int* cursor  = row_ptr + (N + 1);                // N (aliases counts)
    int* bsums   = cursor + N;                       // nb
    int* boffs   = bsums + nb;                       // nb

    float* out_lsm = (float*)d_out;
    float* out_emb = out_lsm + (size_t)N * CDIM;

    // ---- CSR build ----
    hipMemsetAsync(cursor, 0, (size_t)N * sizeof(int), stream);
    hist_kernel<<<(E + 255) / 256, 256, 0, stream>>>(edst, cursor, E);
    scan_sums<<<nb, 256, 0, stream>>>(cursor, bsums, N);
    scan_offsets<<<1, 64, 0, stream>>>(bsums, boffs, nb, row_ptr, N, E);
    scan_write<<<nb, 256, 0, stream>>>(cursor, boffs, row_ptr, cursor, N);
    fill_kernel<<<(E + 255) / 256, 256, 0, stream>>>(esrc, edst, ew, cursor,
                                                     es_packed, E);
    bn_prep<<<1, 128, 0, stream>>>(b1, gamma1, beta1, mean1, var1, scale, shift);

    // ---- layer 1 ----
    const int ntiles = (N + 127) / 128;
    gemm_xw1<<<ntiles, 256, 0, stream>>>(features, W1, xw1b, N);
    gather1_kernel<<<(N + 3) / 4, 256, 0, stream>>>(xw1b, row_ptr, es_packed,
                                                    scale, shift, hb, N);
    // ---- layer 2 ----
    gemm_xw2<<<ntiles, 256, 0, stream>>>(hb, W2, xw2b, N);
    gather2_final<<<(N + 3) / 4, 256, 0, stream>>>(xw2b, row_ptr, es_packed,
                                                   b2, prev, sens, ins,
                                                   out_lsm, out_emb, N);
}